// Round 9
// baseline (143.192 us; speedup 1.0000x reference)
//
#include <hip/hip_runtime.h>

#define BB 4
#define NN 512
#define MM 4096
#define DD 256
#define HH 8
#define HDD 32

typedef __attribute__((ext_vector_type(8))) short bf16x8;
typedef __attribute__((ext_vector_type(4))) float f32x4;
typedef __attribute__((ext_vector_type(4))) unsigned int u32x4;

__device__ __forceinline__ unsigned short f2b(float f) {
    union { float f; unsigned u; } v; v.f = f;
    unsigned r = v.u + 0x7fffu + ((v.u >> 16) & 1u);
    return (unsigned short)(r >> 16);
}
__device__ __forceinline__ float b2f(unsigned short u) {
    union { unsigned u; float f; } v; v.u = ((unsigned)u) << 16;
    return v.f;
}
// packed f32x2 -> bf16x2 (RNE), gfx950 has the instruction but no builtin
__device__ __forceinline__ unsigned cvt_pk_bf16(float lo, float hi) {
    unsigned r;
    asm("v_cvt_pk_bf16_f32 %0, %1, %2" : "=v"(r) : "v"(lo), "v"(hi));
    return r;
}

// ---------------------------------------------------------------------------
// feats f32 -> bf16 (both tensors, one launch)
// ---------------------------------------------------------------------------
__global__ __launch_bounds__(256) void convert_feats(
    const float* __restrict__ amr, const float* __restrict__ vis,
    unsigned short* __restrict__ da, unsigned short* __restrict__ dv)
{
    const int bx = blockIdx.x;
    const float* s; unsigned short* d; int i;
    if (bx < 512) { s = amr; d = da; i = bx * 256 + threadIdx.x; }
    else          { s = vis; d = dv; i = (bx - 512) * 256 + threadIdx.x; }
    const float4 v = ((const float4*)s)[i];
    ushort4 o;
    o.x = f2b(v.x); o.y = f2b(v.y); o.z = f2b(v.z); o.w = f2b(v.w);
    ((ushort4*)d)[i] = o;
}

struct WPack { const float* s[6]; unsigned short* d[6]; };
__global__ __launch_bounds__(256) void convert_w(WPack p)
{
    const int mat = blockIdx.x >> 8;
    const int k = blockIdx.x & 255;
    const int c = threadIdx.x;
    p.d[mat][(size_t)c * DD + k] = f2b(p.s[mat][(size_t)k * DD + c]);
}

// V transposes, both tensors in one launch. grid (18, 32, 4)
__global__ __launch_bounds__(256) void transpose_all(
    const unsigned short* __restrict__ visV,
    const unsigned short* __restrict__ amrV,
    unsigned short* __restrict__ VTv, unsigned short* __restrict__ VTa)
{
    const int bx = blockIdx.x;
    const unsigned short* X; unsigned short* VT; int SEQ, mb;
    if (bx < 16) { X = visV; VT = VTv; SEQ = MM; mb = bx; }
    else         { X = amrV; VT = VTa; SEQ = NN; mb = bx - 16; }
    const int m = mb * 256 + threadIdx.x;
    const int c0 = blockIdx.y * 8;
    const int b = blockIdx.z;
    const bf16x8 v = *(const bf16x8*)&X[((size_t)b * SEQ + m) * DD + c0];
    #pragma unroll
    for (int j = 0; j < 8; ++j)
        VT[((size_t)b * DD + c0 + j) * SEQ + m] = (unsigned short)v[j];
}

// ---------------------------------------------------------------------------
// Shared 64x64 MFMA GEMM tile body (K=256)
// ---------------------------------------------------------------------------
template<bool OUTPROJ>
__device__ __forceinline__ void gemm_tile(
    const unsigned short* __restrict__ A,
    const unsigned short* __restrict__ Wt,
    float outscale,
    const float* __restrict__ bias,
    const float* __restrict__ feats,
    unsigned short* __restrict__ Cb,
    float* __restrict__ Cf,
    int r0, int c0,
    unsigned short (*As)[72], unsigned short (*Ws)[72])
{
    const int tid = threadIdx.x;
    const int lane = tid & 63, w = tid >> 6;
    const int rq = (w >> 1) * 32, cq = (w & 1) * 32;
    const int srow = tid >> 2, skc = (tid & 3) * 16;
    const int g = lane >> 4, cl = lane & 15;

    f32x4 acc[2][2] = {};

    for (int ks = 0; ks < DD; ks += 64) {
        __syncthreads();
        {
            const unsigned short* ga = &A[(size_t)(r0 + srow) * DD + ks + skc];
            *(bf16x8*)&As[srow][skc]     = *(const bf16x8*)ga;
            *(bf16x8*)&As[srow][skc + 8] = *(const bf16x8*)(ga + 8);
            const unsigned short* gw = &Wt[(size_t)(c0 + srow) * DD + ks + skc];
            *(bf16x8*)&Ws[srow][skc]     = *(const bf16x8*)gw;
            *(bf16x8*)&Ws[srow][skc + 8] = *(const bf16x8*)(gw + 8);
        }
        __syncthreads();
        #pragma unroll
        for (int kh = 0; kh < 2; ++kh) {
            const int kk = kh * 32 + g * 8;
            const bf16x8 a0 = *(const bf16x8*)&As[rq + cl][kk];
            const bf16x8 a1 = *(const bf16x8*)&As[rq + 16 + cl][kk];
            const bf16x8 b0 = *(const bf16x8*)&Ws[cq + cl][kk];
            const bf16x8 b1 = *(const bf16x8*)&Ws[cq + 16 + cl][kk];
            acc[0][0] = __builtin_amdgcn_mfma_f32_16x16x32_bf16(a0, b0, acc[0][0], 0, 0, 0);
            acc[0][1] = __builtin_amdgcn_mfma_f32_16x16x32_bf16(a0, b1, acc[0][1], 0, 0, 0);
            acc[1][0] = __builtin_amdgcn_mfma_f32_16x16x32_bf16(a1, b0, acc[1][0], 0, 0, 0);
            acc[1][1] = __builtin_amdgcn_mfma_f32_16x16x32_bf16(a1, b1, acc[1][1], 0, 0, 0);
        }
    }

    #pragma unroll
    for (int sr = 0; sr < 2; ++sr)
    #pragma unroll
    for (int sc = 0; sc < 2; ++sc) {
        const int col = c0 + cq + sc * 16 + cl;
        #pragma unroll
        for (int reg = 0; reg < 4; ++reg) {
            const int row = r0 + rq + sr * 16 + g * 4 + reg;
            const size_t idx = (size_t)row * DD + col;
            if (OUTPROJ) {
                Cf[idx] = (acc[sr][sc][reg] + bias[col]) * feats[idx];
            } else {
                Cb[idx] = f2b(acc[sr][sc][reg] * outscale);
            }
        }
    }
}

// All 4 input projections in one launch. x: 32|32|256|256 (576), y = 4.
struct InPack {
    const unsigned short* A[4];
    const unsigned short* Wt[4];
    unsigned short* C[4];
    float scale[4];
};
__global__ __launch_bounds__(256) void gemm_in(InPack p)
{
    __shared__ unsigned short As[64][72];
    __shared__ unsigned short Ws[64][72];
    const int bx = blockIdx.x;
    int which, rb;
    if (bx < 32)       { which = 0; rb = bx; }
    else if (bx < 64)  { which = 1; rb = bx - 32; }
    else if (bx < 320) { which = 2; rb = bx - 64; }
    else               { which = 3; rb = bx - 320; }
    gemm_tile<false>(p.A[which], p.Wt[which], p.scale[which], nullptr, nullptr,
                     p.C[which], nullptr, rb * 64, blockIdx.y * 64, As, Ws);
}

// Both output projections in one launch. x: 32 amr | 256 vis (288), y = 4.
struct OutPack {
    const unsigned short* A[2];
    const unsigned short* Wt[2];
    const float* bias[2];
    const float* feats[2];
    float* O[2];
};
__global__ __launch_bounds__(256) void gemm_out(OutPack p)
{
    __shared__ unsigned short As[64][72];
    __shared__ unsigned short Ws[64][72];
    const int bx = blockIdx.x;
    const int which = (bx < 32) ? 0 : 1;
    const int rb = (bx < 32) ? bx : bx - 32;
    gemm_tile<true>(p.A[which], p.Wt[which], 1.f, p.bias[which], p.feats[which],
                    nullptr, p.O[which], rb * 64, blockIdx.y * 64, As, Ws);
}

// ---------------------------------------------------------------------------
// Attention body v5: ZERO-LDS main loop.
// Swapped QK^T leaves P[q=cl][m=kf*16+g*4+reg] in-lane; cvt_pk packs pairs.
// PV uses a permuted m-order pi(g*8+j) = mh*32+(j>>2)*16+g*4+(j&3) applied to
// BOTH operands: the lane's own packed dwords ARE the A-frag, and V's B-frag
// loads the same permuted order (two 8B loads per (mh,sub)). No P LDS
// round-trip, no bank conflicts, LDS = mask only.
// ---------------------------------------------------------------------------
template<int SEQK, int SPLIT, bool HAS_MASK>
__device__ __forceinline__ void attn_body(
    int bid,
    const unsigned short* __restrict__ Qb,
    const unsigned short* __restrict__ Kb,
    const unsigned short* __restrict__ VTb,
    const int* __restrict__ mask,
    unsigned short* __restrict__ ctx,
    float* __restrict__ Pl, unsigned short* __restrict__ PaccB,
    int NQ, float* maskadd)
{
    constexpr int KCHUNK = SEQK / SPLIT;
    constexpr int NT = KCHUNK / 64;

    const int tid = threadIdx.x;
    const int lane = tid & 63, w = tid >> 6;
    const int g = lane >> 4, cl = lane & 15;

    const int nqt = NQ / 128;
    int bi = bid;
    const int sp = bi % SPLIT; bi /= SPLIT;
    const int qt = bi % nqt;   bi /= nqt;
    const int h  = bi % HH;
    const int b  = bi / HH;
    const int q0 = qt * 128 + w * 32;
    const int kv0 = sp * KCHUNK;

    if (HAS_MASK) {
        for (int i = tid; i < SEQK; i += 256)
            maskadd[i] = mask[b * SEQK + i] ? -1e30f : 0.f;
        __syncthreads();
    }

    bf16x8 aq[2];
    aq[0] = *(const bf16x8*)&Qb[((size_t)b * NQ + q0 + cl) * DD + h * HDD + g * 8];
    aq[1] = *(const bf16x8*)&Qb[((size_t)b * NQ + q0 + 16 + cl) * DD + h * HDD + g * 8];
    const unsigned short* Kbase = &Kb[(size_t)b * SEQK * DD + h * HDD + g * 8];
    const unsigned short* Vbase = &VTb[((size_t)b * DD + h * HDD) * SEQK];

    float lsum[2] = {0.f, 0.f};
    f32x4 acc[2][2] = {};   // [qg][sub]

    bf16x8 Kc[4], Kn[4];
    #pragma unroll
    for (int kf = 0; kf < 4; ++kf)
        Kc[kf] = *(const bf16x8*)&Kbase[(size_t)(kv0 + kf * 16 + cl) * DD];

    for (int t = 0; t < NT; ++t) {
        const int m0 = kv0 + t * 64;

        // prefetch next K tile's frags (hidden under this tile's compute)
        if (t + 1 < NT) {
            #pragma unroll
            for (int kf = 0; kf < 4; ++kf)
                Kn[kf] = *(const bf16x8*)&Kbase[(size_t)(m0 + 64 + kf * 16 + cl) * DD];
        }

        // swapped QK^T: lane holds q=cl, keys kf*16 + g*4 + reg
        f32x4 s[2][4];
        #pragma unroll
        for (int kf = 0; kf < 4; ++kf) {
            const f32x4 z = {0.f, 0.f, 0.f, 0.f};
            s[0][kf] = __builtin_amdgcn_mfma_f32_16x16x32_bf16(Kc[kf], aq[0], z, 0, 0, 0);
            s[1][kf] = __builtin_amdgcn_mfma_f32_16x16x32_bf16(Kc[kf], aq[1], z, 0, 0, 0);
        }

        // V frags in permuted m-order: lane (g,cl) takes m = mh*32+g*4+{0..3}
        // and m = mh*32+16+g*4+{0..3}  (two 8B loads, issued early)
        uint2 vlo[2][2], vhi[2][2];
        #pragma unroll
        for (int mh = 0; mh < 2; ++mh)
            #pragma unroll
            for (int sub = 0; sub < 2; ++sub) {
                const unsigned short* vp =
                    &Vbase[(size_t)(sub * 16 + cl) * SEQK + m0 + mh * 32 + g * 4];
                vlo[mh][sub] = *(const uint2*)vp;
                vhi[mh][sub] = *(const uint2*)(vp + 16);
            }

        // P = exp2(s [+mask]); pack pairs in-register (no LDS)
        uint2 X[2][4];
        #pragma unroll
        for (int kf = 0; kf < 4; ++kf) {
            f32x4 madd;
            if (HAS_MASK)
                madd = *(const f32x4*)&maskadd[m0 + kf * 16 + g * 4];
            #pragma unroll
            for (int qg = 0; qg < 2; ++qg) {
                const float p0 = exp2f(s[qg][kf][0] + (HAS_MASK ? madd[0] : 0.f));
                const float p1 = exp2f(s[qg][kf][1] + (HAS_MASK ? madd[1] : 0.f));
                const float p2 = exp2f(s[qg][kf][2] + (HAS_MASK ? madd[2] : 0.f));
                const float p3 = exp2f(s[qg][kf][3] + (HAS_MASK ? madd[3] : 0.f));
                lsum[qg] += (p0 + p1) + (p2 + p3);
                X[qg][kf].x = cvt_pk_bf16(p0, p1);
                X[qg][kf].y = cvt_pk_bf16(p2, p3);
            }
        }

        // PV in permuted order: pa = [X[2mh].x, X[2mh].y, X[2mh+1].x, X[2mh+1].y]
        #pragma unroll
        for (int mh = 0; mh < 2; ++mh) {
            union { u32x4 u; bf16x8 b; } pa0, pa1;
            pa0.u[0] = X[0][mh * 2].x;     pa0.u[1] = X[0][mh * 2].y;
            pa0.u[2] = X[0][mh * 2 + 1].x; pa0.u[3] = X[0][mh * 2 + 1].y;
            pa1.u[0] = X[1][mh * 2].x;     pa1.u[1] = X[1][mh * 2].y;
            pa1.u[2] = X[1][mh * 2 + 1].x; pa1.u[3] = X[1][mh * 2 + 1].y;
            #pragma unroll
            for (int sub = 0; sub < 2; ++sub) {
                union { u32x4 u; bf16x8 b; } pv;
                pv.u[0] = vlo[mh][sub].x; pv.u[1] = vlo[mh][sub].y;
                pv.u[2] = vhi[mh][sub].x; pv.u[3] = vhi[mh][sub].y;
                acc[0][sub] = __builtin_amdgcn_mfma_f32_16x16x32_bf16(pa0.b, pv.b, acc[0][sub], 0, 0, 0);
                acc[1][sub] = __builtin_amdgcn_mfma_f32_16x16x32_bf16(pa1.b, pv.b, acc[1][sub], 0, 0, 0);
            }
        }

        #pragma unroll
        for (int kf = 0; kf < 4; ++kf) Kc[kf] = Kn[kf];
    }

    // total l per q=cl: reduce across the 4 g-groups
    #pragma unroll
    for (int qg = 0; qg < 2; ++qg) {
        lsum[qg] += __shfl_xor(lsum[qg], 16);
        lsum[qg] += __shfl_xor(lsum[qg], 32);
    }

    if (SPLIT > 1) {
        const int pb = bid;
        #pragma unroll
        for (int qg = 0; qg < 2; ++qg) {
            #pragma unroll
            for (int sub = 0; sub < 2; ++sub)
                #pragma unroll
                for (int reg = 0; reg < 4; ++reg) {
                    const int wq = w * 32 + qg * 16 + g * 4 + reg;
                    PaccB[((size_t)pb * 128 + wq) * 32 + sub * 16 + cl]
                        = f2b(acc[qg][sub][reg]);
                }
            if (g == 0)
                Pl[(size_t)pb * 128 + w * 32 + qg * 16 + cl] = lsum[qg];
        }
    } else {
        // redistribute l: acc rows are q = g*4+reg; lsum lives at lane cl=q
        float linv[2][4];
        #pragma unroll
        for (int qg = 0; qg < 2; ++qg)
            #pragma unroll
            for (int reg = 0; reg < 4; ++reg)
                linv[qg][reg] = __shfl(lsum[qg], g * 4 + reg);
        #pragma unroll
        for (int qg = 0; qg < 2; ++qg)
            #pragma unroll
            for (int sub = 0; sub < 2; ++sub)
                #pragma unroll
                for (int reg = 0; reg < 4; ++reg) {
                    const int q = q0 + qg * 16 + g * 4 + reg;
                    ctx[((size_t)b * NQ + q) * DD + h * HDD + sub * 16 + cl]
                        = f2b(acc[qg][sub][reg] / linv[qg][reg]);
                }
    }
}

// Fused: dir A (blocks 0..1023, SPLIT=8) + dir B (1024..2047), uniform NT=8.
__global__ __launch_bounds__(256) void attn_fused(
    const unsigned short* __restrict__ amr_qk,
    const unsigned short* __restrict__ vis_qk,
    const unsigned short* __restrict__ VT_vis,
    const unsigned short* __restrict__ VT_amr,
    const int* __restrict__ mask,
    unsigned short* __restrict__ ctx1,
    float* __restrict__ Pl, unsigned short* __restrict__ PaccB)
{
    __shared__ float maskadd[NN];
    constexpr int NA = (NN / 128) * HH * BB * 8;   // 1024 dir-A blocks
    if (blockIdx.x < NA) {
        attn_body<MM, 8, false>(blockIdx.x, amr_qk, vis_qk, VT_vis, nullptr,
                                nullptr, Pl, PaccB, NN, maskadd);
    } else {
        attn_body<NN, 1, true>(blockIdx.x - NA, vis_qk, amr_qk, VT_amr, mask,
                               ctx1, nullptr, nullptr, MM, maskadd);
    }
}

// Combine 8 split partials (bf16 acc, f32 l): out = sum(acc)/sum(l)
__global__ __launch_bounds__(256) void combine_split(
    const float* __restrict__ Pl, const unsigned short* __restrict__ PaccB,
    unsigned short* __restrict__ ctx)
{
    const int tid = threadIdx.x;
    const int q = tid >> 1, ch = tid & 1;
    const int bqt = blockIdx.x;
    const int qt = bqt & 3, h = (bqt >> 2) & 7, b = bqt >> 5;
    const int pb0 = bqt * 8;

    float denom = 0.f;
    float o[16] = {};
    #pragma unroll
    for (int sp = 0; sp < 8; ++sp) {
        const size_t base = ((size_t)(pb0 + sp) * 128 + q) * 32 + ch * 16;
        const bf16x8 a0 = *(const bf16x8*)&PaccB[base];
        const bf16x8 a1 = *(const bf16x8*)&PaccB[base + 8];
        #pragma unroll
        for (int j = 0; j < 8; ++j) {
            o[j]     += b2f((unsigned short)a0[j]);
            o[8 + j] += b2f((unsigned short)a1[j]);
        }
        denom += Pl[(size_t)(pb0 + sp) * 128 + q];
    }
    const float inv = 1.f / denom;

    unsigned short* dst = &ctx[((size_t)b * NN + qt * 128 + q) * DD + h * HDD + ch * 16];
    ushort4 u;
    #pragma unroll
    for (int j4 = 0; j4 < 4; ++j4) {
        u.x = f2b(o[j4 * 4 + 0] * inv); u.y = f2b(o[j4 * 4 + 1] * inv);
        u.z = f2b(o[j4 * 4 + 2] * inv); u.w = f2b(o[j4 * 4 + 3] * inv);
        *(ushort4*)(dst + j4 * 4) = u;
    }
}

// ---------------------------------------------------------------------------
extern "C" void kernel_launch(void* const* d_in, const int* in_sizes, int n_in,
                              void* d_out, int out_size, void* d_ws, size_t ws_size,
                              hipStream_t stream)
{
    const float* amr_feats    = (const float*)d_in[0];
    const int*   amr_pad_mask = (const int*)d_in[1];
    const float* visual_feats = (const float*)d_in[2];
    const float* W_amr_qk     = (const float*)d_in[3];
    const float* W_amr_v      = (const float*)d_in[4];
    const float* W_vis_qk     = (const float*)d_in[5];
    const float* W_vis_v      = (const float*)d_in[6];
    const float* W_amr_out    = (const float*)d_in[7];
    const float* b_amr_out    = (const float*)d_in[8];
    const float* W_vis_out    = (const float*)d_in[9];
    const float* b_vis_out    = (const float*)d_in[10];

    // bf16 workspace (u16 offsets), total 48.0 MB
    unsigned short* ws = (unsigned short*)d_ws;
    unsigned short* amr_fb     = ws;                    // dead after gemm_in
    unsigned short* vis_fb     = ws + 524288;           // dead after gemm_in
    unsigned short* Wt_amr_qk  = ws + 4718592;
    unsigned short* Wt_amr_v   = ws + 4784128;
    unsigned short* Wt_vis_qk  = ws + 4849664;
    unsigned short* Wt_vis_v   = ws + 4915200;
    unsigned short* Wt_amr_out = ws + 4980736;
    unsigned short* Wt_vis_out = ws + 5046272;
    unsigned short* amr_qk_b   = ws + 5111808;
    unsigned short* amr_v_b    = ws + 5636096;
    unsigned short* vis_qk_b   = ws + 6160384;
    unsigned short* vis_v_b    = ws + 10354688;
    unsigned short* ctx0_b     = ws + 14548992;
    unsigned short* ctx1_b     = ws + 15073280;
    unsigned short* VT_vis     = ws + 19267584;
    unsigned short* VT_amr     = ws + 23461888;
    // split partials alias the dead amr_fb/vis_fb staging region
    float* Pl             = (float*)ws;          // 1024*128 f32
    unsigned short* PaccB = ws + 262144;         // 1024*128*32 bf16

    float* out0 = (float*)d_out;
    float* out1 = out0 + (size_t)BB * NN * DD;

    // sqrt( HD^-0.5 * log2(e) ) folded into BOTH qk projections -> exp2 domain
    const float SQS = 0.50500976f;

    // 0) conversions (2 launches)
    convert_feats<<<4608, 256, 0, stream>>>(amr_feats, visual_feats, amr_fb, vis_fb);
    WPack wp;
    wp.s[0] = W_amr_qk;  wp.d[0] = Wt_amr_qk;
    wp.s[1] = W_amr_v;   wp.d[1] = Wt_amr_v;
    wp.s[2] = W_vis_qk;  wp.d[2] = Wt_vis_qk;
    wp.s[3] = W_vis_v;   wp.d[3] = Wt_vis_v;
    wp.s[4] = W_amr_out; wp.d[4] = Wt_amr_out;
    wp.s[5] = W_vis_out; wp.d[5] = Wt_vis_out;
    convert_w<<<1536, 256, 0, stream>>>(wp);

    // 1) all 4 input projections, one launch
    InPack ip;
    ip.A[0] = amr_fb; ip.Wt[0] = Wt_amr_qk; ip.C[0] = amr_qk_b; ip.scale[0] = SQS;
    ip.A[1] = amr_fb; ip.Wt[1] = Wt_amr_v;  ip.C[1] = amr_v_b;  ip.scale[1] = 1.f;
    ip.A[2] = vis_fb; ip.Wt[2] = Wt_vis_qk; ip.C[2] = vis_qk_b; ip.scale[2] = SQS;
    ip.A[3] = vis_fb; ip.Wt[3] = Wt_vis_v;  ip.C[3] = vis_v_b;  ip.scale[3] = 1.f;
    gemm_in<<<dim3(576, 4), 256, 0, stream>>>(ip);

    // 1b) V transposes, one launch
    transpose_all<<<dim3(18, 32, 4), 256, 0, stream>>>(vis_v_b, amr_v_b, VT_vis, VT_amr);

    // 2) both attention directions in ONE launch (uniform 8-tile blocks)
    attn_fused<<<2048, 256, 0, stream>>>(
        amr_qk_b, vis_qk_b, VT_vis, VT_amr, amr_pad_mask, ctx1_b, Pl, PaccB);
    combine_split<<<128, 256, 0, stream>>>(Pl, PaccB, ctx0_b);

    // 3) both output projections, one launch
    OutPack op;
    op.A[0] = ctx0_b; op.Wt[0] = Wt_amr_out; op.bias[0] = b_amr_out;
    op.feats[0] = amr_feats;    op.O[0] = out0;
    op.A[1] = ctx1_b; op.Wt[1] = Wt_vis_out; op.bias[1] = b_vis_out;
    op.feats[1] = visual_feats; op.O[1] = out1;
    gemm_out<<<dim3(288, 4), 256, 0, stream>>>(op);
}

// Round 10
// 117.340 us; speedup vs baseline: 1.2203x; 1.2203x over previous
//
#include <hip/hip_runtime.h>

#define BB 4
#define NN 512
#define MM 4096
#define DD 256
#define HH 8
#define HDD 32

typedef __attribute__((ext_vector_type(8))) short bf16x8;
typedef __attribute__((ext_vector_type(4))) float f32x4;
typedef __attribute__((ext_vector_type(4))) unsigned int u32x4;

__device__ __forceinline__ unsigned short f2b(float f) {
    union { float f; unsigned u; } v; v.f = f;
    unsigned r = v.u + 0x7fffu + ((v.u >> 16) & 1u);
    return (unsigned short)(r >> 16);
}
__device__ __forceinline__ float b2f(unsigned short u) {
    union { unsigned u; float f; } v; v.u = ((unsigned)u) << 16;
    return v.f;
}
// packed f32x2 -> bf16x2 (RNE), gfx950 has the instruction but no builtin
__device__ __forceinline__ unsigned cvt_pk_bf16(float lo, float hi) {
    unsigned r;
    asm("v_cvt_pk_bf16_f32 %0, %1, %2" : "=v"(r) : "v"(lo), "v"(hi));
    return r;
}

// ---------------------------------------------------------------------------
// feats f32 -> bf16 (both tensors, one launch)
// ---------------------------------------------------------------------------
__global__ __launch_bounds__(256) void convert_feats(
    const float* __restrict__ amr, const float* __restrict__ vis,
    unsigned short* __restrict__ da, unsigned short* __restrict__ dv)
{
    const int bx = blockIdx.x;
    const float* s; unsigned short* d; int i;
    if (bx < 512) { s = amr; d = da; i = bx * 256 + threadIdx.x; }
    else          { s = vis; d = dv; i = (bx - 512) * 256 + threadIdx.x; }
    const float4 v = ((const float4*)s)[i];
    ushort4 o;
    o.x = f2b(v.x); o.y = f2b(v.y); o.z = f2b(v.z); o.w = f2b(v.w);
    ((ushort4*)d)[i] = o;
}

struct WPack { const float* s[6]; unsigned short* d[6]; };
__global__ __launch_bounds__(256) void convert_w(WPack p)
{
    const int mat = blockIdx.x >> 8;
    const int k = blockIdx.x & 255;
    const int c = threadIdx.x;
    p.d[mat][(size_t)c * DD + k] = f2b(p.s[mat][(size_t)k * DD + c]);
}

// ---------------------------------------------------------------------------
// V transposes with the PV-fragment permutation baked in.
// Within each 32-m block, position p = g*8+j  holds actual
// m-offset r = (j>>2)*16 + g*4 + (j&3)   (p = ((r&15)>>2)*8 + (r>>4)*4 + (r&3)).
// Then the PV B-frag is ONE contiguous 16B load at (32-blk base + g*8).
// ---------------------------------------------------------------------------
__global__ __launch_bounds__(256) void transpose_all(
    const unsigned short* __restrict__ visV,
    const unsigned short* __restrict__ amrV,
    unsigned short* __restrict__ VTv, unsigned short* __restrict__ VTa)
{
    const int bx = blockIdx.x;
    const unsigned short* X; unsigned short* VT; int SEQ, mb;
    if (bx < 16) { X = visV; VT = VTv; SEQ = MM; mb = bx; }
    else         { X = amrV; VT = VTa; SEQ = NN; mb = bx - 16; }
    const int m = mb * 256 + threadIdx.x;
    const int r = m & 31;
    const int p = ((r & 15) >> 2) * 8 + (r >> 4) * 4 + (r & 3);
    const int mstore = (m & ~31) | p;
    const int c0 = blockIdx.y * 8;
    const int b = blockIdx.z;
    const bf16x8 v = *(const bf16x8*)&X[((size_t)b * SEQ + m) * DD + c0];
    #pragma unroll
    for (int j = 0; j < 8; ++j)
        VT[((size_t)b * DD + c0 + j) * SEQ + mstore] = (unsigned short)v[j];
}

// ---------------------------------------------------------------------------
// Shared 64x64 MFMA GEMM tile body (K=256)
// ---------------------------------------------------------------------------
template<bool OUTPROJ>
__device__ __forceinline__ void gemm_tile(
    const unsigned short* __restrict__ A,
    const unsigned short* __restrict__ Wt,
    float outscale,
    const float* __restrict__ bias,
    const float* __restrict__ feats,
    unsigned short* __restrict__ Cb,
    float* __restrict__ Cf,
    int r0, int c0,
    unsigned short (*As)[72], unsigned short (*Ws)[72])
{
    const int tid = threadIdx.x;
    const int lane = tid & 63, w = tid >> 6;
    const int rq = (w >> 1) * 32, cq = (w & 1) * 32;
    const int srow = tid >> 2, skc = (tid & 3) * 16;
    const int g = lane >> 4, cl = lane & 15;

    f32x4 acc[2][2] = {};

    for (int ks = 0; ks < DD; ks += 64) {
        __syncthreads();
        {
            const unsigned short* ga = &A[(size_t)(r0 + srow) * DD + ks + skc];
            *(bf16x8*)&As[srow][skc]     = *(const bf16x8*)ga;
            *(bf16x8*)&As[srow][skc + 8] = *(const bf16x8*)(ga + 8);
            const unsigned short* gw = &Wt[(size_t)(c0 + srow) * DD + ks + skc];
            *(bf16x8*)&Ws[srow][skc]     = *(const bf16x8*)gw;
            *(bf16x8*)&Ws[srow][skc + 8] = *(const bf16x8*)(gw + 8);
        }
        __syncthreads();
        #pragma unroll
        for (int kh = 0; kh < 2; ++kh) {
            const int kk = kh * 32 + g * 8;
            const bf16x8 a0 = *(const bf16x8*)&As[rq + cl][kk];
            const bf16x8 a1 = *(const bf16x8*)&As[rq + 16 + cl][kk];
            const bf16x8 b0 = *(const bf16x8*)&Ws[cq + cl][kk];
            const bf16x8 b1 = *(const bf16x8*)&Ws[cq + 16 + cl][kk];
            acc[0][0] = __builtin_amdgcn_mfma_f32_16x16x32_bf16(a0, b0, acc[0][0], 0, 0, 0);
            acc[0][1] = __builtin_amdgcn_mfma_f32_16x16x32_bf16(a0, b1, acc[0][1], 0, 0, 0);
            acc[1][0] = __builtin_amdgcn_mfma_f32_16x16x32_bf16(a1, b0, acc[1][0], 0, 0, 0);
            acc[1][1] = __builtin_amdgcn_mfma_f32_16x16x32_bf16(a1, b1, acc[1][1], 0, 0, 0);
        }
    }

    #pragma unroll
    for (int sr = 0; sr < 2; ++sr)
    #pragma unroll
    for (int sc = 0; sc < 2; ++sc) {
        const int col = c0 + cq + sc * 16 + cl;
        #pragma unroll
        for (int reg = 0; reg < 4; ++reg) {
            const int row = r0 + rq + sr * 16 + g * 4 + reg;
            const size_t idx = (size_t)row * DD + col;
            if (OUTPROJ) {
                Cf[idx] = (acc[sr][sc][reg] + bias[col]) * feats[idx];
            } else {
                Cb[idx] = f2b(acc[sr][sc][reg] * outscale);
            }
        }
    }
}

// All 4 input projections in one launch. x: 32|32|256|256 (576), y = 4.
struct InPack {
    const unsigned short* A[4];
    const unsigned short* Wt[4];
    unsigned short* C[4];
    float scale[4];
};
__global__ __launch_bounds__(256) void gemm_in(InPack p)
{
    __shared__ unsigned short As[64][72];
    __shared__ unsigned short Ws[64][72];
    const int bx = blockIdx.x;
    int which, rb;
    if (bx < 32)       { which = 0; rb = bx; }
    else if (bx < 64)  { which = 1; rb = bx - 32; }
    else if (bx < 320) { which = 2; rb = bx - 64; }
    else               { which = 3; rb = bx - 320; }
    gemm_tile<false>(p.A[which], p.Wt[which], p.scale[which], nullptr, nullptr,
                     p.C[which], nullptr, rb * 64, blockIdx.y * 64, As, Ws);
}

// Both output projections in one launch. x: 32 amr | 256 vis (288), y = 4.
struct OutPack {
    const unsigned short* A[2];
    const unsigned short* Wt[2];
    const float* bias[2];
    const float* feats[2];
    float* O[2];
};
__global__ __launch_bounds__(256) void gemm_out(OutPack p)
{
    __shared__ unsigned short As[64][72];
    __shared__ unsigned short Ws[64][72];
    const int bx = blockIdx.x;
    const int which = (bx < 32) ? 0 : 1;
    const int rb = (bx < 32) ? bx : bx - 32;
    gemm_tile<true>(p.A[which], p.Wt[which], 1.f, p.bias[which], p.feats[which],
                    nullptr, p.O[which], rb * 64, blockIdx.y * 64, As, Ws);
}

// ---------------------------------------------------------------------------
// Attention body v6: zero-LDS P + permuted-VT so every V B-frag is a single
// contiguous 16B load (4 K-loads + 4 V-loads of 16B per 64-key tile, no DS).
// Swapped QK^T leaves P[q=cl][m=kf*16+g*4+reg] in-lane; cvt_pk packs pairs;
// the packed dwords [X[2mh].x, X[2mh].y, X[2mh+1].x, X[2mh+1].y] ARE the
// PV A-frag under the permutation baked into VT by transpose_all.
// ---------------------------------------------------------------------------
template<int SEQK, int SPLIT, bool HAS_MASK>
__device__ __forceinline__ void attn_body(
    int bid,
    const unsigned short* __restrict__ Qb,
    const unsigned short* __restrict__ Kb,
    const unsigned short* __restrict__ VTb,
    const int* __restrict__ mask,
    unsigned short* __restrict__ ctx,
    float* __restrict__ Pl, unsigned short* __restrict__ PaccB,
    int NQ, float* maskadd)
{
    constexpr int KCHUNK = SEQK / SPLIT;
    constexpr int NT = KCHUNK / 64;

    const int tid = threadIdx.x;
    const int lane = tid & 63, w = tid >> 6;
    const int g = lane >> 4, cl = lane & 15;

    const int nqt = NQ / 128;
    int bi = bid;
    const int sp = bi % SPLIT; bi /= SPLIT;
    const int qt = bi % nqt;   bi /= nqt;
    const int h  = bi % HH;
    const int b  = bi / HH;
    const int q0 = qt * 128 + w * 32;
    const int kv0 = sp * KCHUNK;

    if (HAS_MASK) {
        for (int i = tid; i < SEQK; i += 256)
            maskadd[i] = mask[b * SEQK + i] ? -1e30f : 0.f;
        __syncthreads();
    }

    bf16x8 aq[2];
    aq[0] = *(const bf16x8*)&Qb[((size_t)b * NQ + q0 + cl) * DD + h * HDD + g * 8];
    aq[1] = *(const bf16x8*)&Qb[((size_t)b * NQ + q0 + 16 + cl) * DD + h * HDD + g * 8];
    const unsigned short* Kbase = &Kb[(size_t)b * SEQK * DD + h * HDD + g * 8];
    const unsigned short* Vbase = &VTb[((size_t)b * DD + h * HDD) * SEQK];

    float lsum[2] = {0.f, 0.f};
    f32x4 acc[2][2] = {};   // [qg][sub]

    bf16x8 Kc[4], Kn[4];
    #pragma unroll
    for (int kf = 0; kf < 4; ++kf)
        Kc[kf] = *(const bf16x8*)&Kbase[(size_t)(kv0 + kf * 16 + cl) * DD];

    for (int t = 0; t < NT; ++t) {
        const int m0 = kv0 + t * 64;

        // prefetch next K tile's frags (hidden under this tile's compute)
        if (t + 1 < NT) {
            #pragma unroll
            for (int kf = 0; kf < 4; ++kf)
                Kn[kf] = *(const bf16x8*)&Kbase[(size_t)(m0 + 64 + kf * 16 + cl) * DD];
        }

        // swapped QK^T: lane holds q=cl, keys kf*16 + g*4 + reg
        f32x4 s[2][4];
        #pragma unroll
        for (int kf = 0; kf < 4; ++kf) {
            const f32x4 z = {0.f, 0.f, 0.f, 0.f};
            s[0][kf] = __builtin_amdgcn_mfma_f32_16x16x32_bf16(Kc[kf], aq[0], z, 0, 0, 0);
            s[1][kf] = __builtin_amdgcn_mfma_f32_16x16x32_bf16(Kc[kf], aq[1], z, 0, 0, 0);
        }

        // V B-frags: single 16B loads from the permuted VT (issued early)
        bf16x8 vv[2][2];
        #pragma unroll
        for (int mh = 0; mh < 2; ++mh)
            #pragma unroll
            for (int sub = 0; sub < 2; ++sub)
                vv[mh][sub] = *(const bf16x8*)
                    &Vbase[(size_t)(sub * 16 + cl) * SEQK + m0 + mh * 32 + g * 8];

        // P = exp2(s [+mask]); pack pairs in-register (no LDS)
        uint2 X[2][4];
        #pragma unroll
        for (int kf = 0; kf < 4; ++kf) {
            f32x4 madd;
            if (HAS_MASK)
                madd = *(const f32x4*)&maskadd[m0 + kf * 16 + g * 4];
            #pragma unroll
            for (int qg = 0; qg < 2; ++qg) {
                const float p0 = exp2f(s[qg][kf][0] + (HAS_MASK ? madd[0] : 0.f));
                const float p1 = exp2f(s[qg][kf][1] + (HAS_MASK ? madd[1] : 0.f));
                const float p2 = exp2f(s[qg][kf][2] + (HAS_MASK ? madd[2] : 0.f));
                const float p3 = exp2f(s[qg][kf][3] + (HAS_MASK ? madd[3] : 0.f));
                lsum[qg] += (p0 + p1) + (p2 + p3);
                X[qg][kf].x = cvt_pk_bf16(p0, p1);
                X[qg][kf].y = cvt_pk_bf16(p2, p3);
            }
        }

        // PV: pa = [X[2mh].x, X[2mh].y, X[2mh+1].x, X[2mh+1].y]; pv = vv
        #pragma unroll
        for (int mh = 0; mh < 2; ++mh) {
            union { u32x4 u; bf16x8 b; } pa0, pa1;
            pa0.u[0] = X[0][mh * 2].x;     pa0.u[1] = X[0][mh * 2].y;
            pa0.u[2] = X[0][mh * 2 + 1].x; pa0.u[3] = X[0][mh * 2 + 1].y;
            pa1.u[0] = X[1][mh * 2].x;     pa1.u[1] = X[1][mh * 2].y;
            pa1.u[2] = X[1][mh * 2 + 1].x; pa1.u[3] = X[1][mh * 2 + 1].y;
            #pragma unroll
            for (int sub = 0; sub < 2; ++sub) {
                acc[0][sub] = __builtin_amdgcn_mfma_f32_16x16x32_bf16(pa0.b, vv[mh][sub], acc[0][sub], 0, 0, 0);
                acc[1][sub] = __builtin_amdgcn_mfma_f32_16x16x32_bf16(pa1.b, vv[mh][sub], acc[1][sub], 0, 0, 0);
            }
        }

        #pragma unroll
        for (int kf = 0; kf < 4; ++kf) Kc[kf] = Kn[kf];
    }

    // total l per q=cl: reduce across the 4 g-groups
    #pragma unroll
    for (int qg = 0; qg < 2; ++qg) {
        lsum[qg] += __shfl_xor(lsum[qg], 16);
        lsum[qg] += __shfl_xor(lsum[qg], 32);
    }

    if (SPLIT > 1) {
        const int pb = bid;
        #pragma unroll
        for (int qg = 0; qg < 2; ++qg) {
            #pragma unroll
            for (int sub = 0; sub < 2; ++sub)
                #pragma unroll
                for (int reg = 0; reg < 4; ++reg) {
                    const int wq = w * 32 + qg * 16 + g * 4 + reg;
                    PaccB[((size_t)pb * 128 + wq) * 32 + sub * 16 + cl]
                        = f2b(acc[qg][sub][reg]);
                }
            if (g == 0)
                Pl[(size_t)pb * 128 + w * 32 + qg * 16 + cl] = lsum[qg];
        }
    } else {
        // redistribute l: acc rows are q = g*4+reg; lsum lives at lane cl=q
        float linv[2][4];
        #pragma unroll
        for (int qg = 0; qg < 2; ++qg)
            #pragma unroll
            for (int reg = 0; reg < 4; ++reg)
                linv[qg][reg] = __shfl(lsum[qg], g * 4 + reg);
        #pragma unroll
        for (int qg = 0; qg < 2; ++qg)
            #pragma unroll
            for (int sub = 0; sub < 2; ++sub)
                #pragma unroll
                for (int reg = 0; reg < 4; ++reg) {
                    const int q = q0 + qg * 16 + g * 4 + reg;
                    ctx[((size_t)b * NQ + q) * DD + h * HDD + sub * 16 + cl]
                        = f2b(acc[qg][sub][reg] / linv[qg][reg]);
                }
    }
}

// Fused: dir A (blocks 0..1023, SPLIT=8) + dir B (1024..2047), uniform NT=8.
__global__ __launch_bounds__(256) void attn_fused(
    const unsigned short* __restrict__ amr_qk,
    const unsigned short* __restrict__ vis_qk,
    const unsigned short* __restrict__ VT_vis,
    const unsigned short* __restrict__ VT_amr,
    const int* __restrict__ mask,
    unsigned short* __restrict__ ctx1,
    float* __restrict__ Pl, unsigned short* __restrict__ PaccB)
{
    __shared__ float maskadd[NN];
    constexpr int NA = (NN / 128) * HH * BB * 8;   // 1024 dir-A blocks
    if (blockIdx.x < NA) {
        attn_body<MM, 8, false>(blockIdx.x, amr_qk, vis_qk, VT_vis, nullptr,
                                nullptr, Pl, PaccB, NN, maskadd);
    } else {
        attn_body<NN, 1, true>(blockIdx.x - NA, vis_qk, amr_qk, VT_amr, mask,
                               ctx1, nullptr, nullptr, MM, maskadd);
    }
}

// Combine 8 split partials (bf16 acc, f32 l): out = sum(acc)/sum(l)
__global__ __launch_bounds__(256) void combine_split(
    const float* __restrict__ Pl, const unsigned short* __restrict__ PaccB,
    unsigned short* __restrict__ ctx)
{
    const int tid = threadIdx.x;
    const int q = tid >> 1, ch = tid & 1;
    const int bqt = blockIdx.x;
    const int qt = bqt & 3, h = (bqt >> 2) & 7, b = bqt >> 5;
    const int pb0 = bqt * 8;

    float denom = 0.f;
    float o[16] = {};
    #pragma unroll
    for (int sp = 0; sp < 8; ++sp) {
        const size_t base = ((size_t)(pb0 + sp) * 128 + q) * 32 + ch * 16;
        const bf16x8 a0 = *(const bf16x8*)&PaccB[base];
        const bf16x8 a1 = *(const bf16x8*)&PaccB[base + 8];
        #pragma unroll
        for (int j = 0; j < 8; ++j) {
            o[j]     += b2f((unsigned short)a0[j]);
            o[8 + j] += b2f((unsigned short)a1[j]);
        }
        denom += Pl[(size_t)(pb0 + sp) * 128 + q];
    }
    const float inv = 1.f / denom;

    unsigned short* dst = &ctx[((size_t)b * NN + qt * 128 + q) * DD + h * HDD + ch * 16];
    ushort4 u;
    #pragma unroll
    for (int j4 = 0; j4 < 4; ++j4) {
        u.x = f2b(o[j4 * 4 + 0] * inv); u.y = f2b(o[j4 * 4 + 1] * inv);
        u.z = f2b(o[j4 * 4 + 2] * inv); u.w = f2b(o[j4 * 4 + 3] * inv);
        *(ushort4*)(dst + j4 * 4) = u;
    }
}

// ---------------------------------------------------------------------------
extern "C" void kernel_launch(void* const* d_in, const int* in_sizes, int n_in,
                              void* d_out, int out_size, void* d_ws, size_t ws_size,
                              hipStream_t stream)
{
    const float* amr_feats    = (const float*)d_in[0];
    const int*   amr_pad_mask = (const int*)d_in[1];
    const float* visual_feats = (const float*)d_in[2];
    const float* W_amr_qk     = (const float*)d_in[3];
    const float* W_amr_v      = (const float*)d_in[4];
    const float* W_vis_qk     = (const float*)d_in[5];
    const float* W_vis_v      = (const float*)d_in[6];
    const float* W_amr_out    = (const float*)d_in[7];
    const float* b_amr_out    = (const float*)d_in[8];
    const float* W_vis_out    = (const float*)d_in[9];
    const float* b_vis_out    = (const float*)d_in[10];

    // bf16 workspace (u16 offsets), total 48.0 MB
    unsigned short* ws = (unsigned short*)d_ws;
    unsigned short* amr_fb     = ws;                    // dead after gemm_in
    unsigned short* vis_fb     = ws + 524288;           // dead after gemm_in
    unsigned short* Wt_amr_qk  = ws + 4718592;
    unsigned short* Wt_amr_v   = ws + 4784128;
    unsigned short* Wt_vis_qk  = ws + 4849664;
    unsigned short* Wt_vis_v   = ws + 4915200;
    unsigned short* Wt_amr_out = ws + 4980736;
    unsigned short* Wt_vis_out = ws + 5046272;
    unsigned short* amr_qk_b   = ws + 5111808;
    unsigned short* amr_v_b    = ws + 5636096;
    unsigned short* vis_qk_b   = ws + 6160384;
    unsigned short* vis_v_b    = ws + 10354688;
    unsigned short* ctx0_b     = ws + 14548992;
    unsigned short* ctx1_b     = ws + 15073280;
    unsigned short* VT_vis     = ws + 19267584;
    unsigned short* VT_amr     = ws + 23461888;
    // split partials alias the dead amr_fb/vis_fb staging region
    float* Pl             = (float*)ws;          // 1024*128 f32
    unsigned short* PaccB = ws + 262144;         // 1024*128*32 bf16

    float* out0 = (float*)d_out;
    float* out1 = out0 + (size_t)BB * NN * DD;

    // sqrt( HD^-0.5 * log2(e) ) folded into BOTH qk projections -> exp2 domain
    const float SQS = 0.50500976f;

    // 0) conversions (2 launches)
    convert_feats<<<4608, 256, 0, stream>>>(amr_feats, visual_feats, amr_fb, vis_fb);
    WPack wp;
    wp.s[0] = W_amr_qk;  wp.d[0] = Wt_amr_qk;
    wp.s[1] = W_amr_v;   wp.d[1] = Wt_amr_v;
    wp.s[2] = W_vis_qk;  wp.d[2] = Wt_vis_qk;
    wp.s[3] = W_vis_v;   wp.d[3] = Wt_vis_v;
    wp.s[4] = W_amr_out; wp.d[4] = Wt_amr_out;
    wp.s[5] = W_vis_out; wp.d[5] = Wt_vis_out;
    convert_w<<<1536, 256, 0, stream>>>(wp);

    // 1) all 4 input projections, one launch
    InPack ip;
    ip.A[0] = amr_fb; ip.Wt[0] = Wt_amr_qk; ip.C[0] = amr_qk_b; ip.scale[0] = SQS;
    ip.A[1] = amr_fb; ip.Wt[1] = Wt_amr_v;  ip.C[1] = amr_v_b;  ip.scale[1] = 1.f;
    ip.A[2] = vis_fb; ip.Wt[2] = Wt_vis_qk; ip.C[2] = vis_qk_b; ip.scale[2] = SQS;
    ip.A[3] = vis_fb; ip.Wt[3] = Wt_vis_v;  ip.C[3] = vis_v_b;  ip.scale[3] = 1.f;
    gemm_in<<<dim3(576, 4), 256, 0, stream>>>(ip);

    // 1b) V transposes (permuted layout), one launch
    transpose_all<<<dim3(18, 32, 4), 256, 0, stream>>>(vis_v_b, amr_v_b, VT_vis, VT_amr);

    // 2) both attention directions in ONE launch (uniform 8-tile blocks)
    attn_fused<<<2048, 256, 0, stream>>>(
        amr_qk_b, vis_qk_b, VT_vis, VT_amr, amr_pad_mask, ctx1_b, Pl, PaccB);
    combine_split<<<128, 256, 0, stream>>>(Pl, PaccB, ctx0_b);

    // 3) both output projections, one launch
    OutPack op;
    op.A[0] = ctx0_b; op.Wt[0] = Wt_amr_out; op.bias[0] = b_amr_out;
    op.feats[0] = amr_feats;    op.O[0] = out0;
    op.A[1] = ctx1_b; op.Wt[1] = Wt_vis_out; op.bias[1] = b_vis_out;
    op.feats[1] = visual_feats; op.O[1] = out1;
    gemm_out<<<dim3(288, 4), 256, 0, stream>>>(op);
}

// Round 11
// 105.645 us; speedup vs baseline: 1.3554x; 1.1107x over previous
//
#include <hip/hip_runtime.h>

#define BB 4
#define NN 512
#define MM 4096
#define DD 256
#define HH 8
#define HDD 32

typedef __attribute__((ext_vector_type(8))) short bf16x8;
typedef __attribute__((ext_vector_type(4))) float f32x4;
typedef __attribute__((ext_vector_type(4))) unsigned int u32x4;

__device__ __forceinline__ unsigned short f2b(float f) {
    union { float f; unsigned u; } v; v.f = f;
    unsigned r = v.u + 0x7fffu + ((v.u >> 16) & 1u);
    return (unsigned short)(r >> 16);
}
__device__ __forceinline__ float b2f(unsigned short u) {
    union { unsigned u; float f; } v; v.u = ((unsigned)u) << 16;
    return v.f;
}
// packed f32x2 -> bf16x2 (RNE), gfx950 has the instruction but no builtin
__device__ __forceinline__ unsigned cvt_pk_bf16(float lo, float hi) {
    unsigned r;
    asm("v_cvt_pk_bf16_f32 %0, %1, %2" : "=v"(r) : "v"(lo), "v"(hi));
    return r;
}

// ---------------------------------------------------------------------------
// feats f32 -> bf16 (both tensors, one launch)
// ---------------------------------------------------------------------------
__global__ __launch_bounds__(256) void convert_feats(
    const float* __restrict__ amr, const float* __restrict__ vis,
    unsigned short* __restrict__ da, unsigned short* __restrict__ dv)
{
    const int bx = blockIdx.x;
    const float* s; unsigned short* d; int i;
    if (bx < 512) { s = amr; d = da; i = bx * 256 + threadIdx.x; }
    else          { s = vis; d = dv; i = (bx - 512) * 256 + threadIdx.x; }
    const float4 v = ((const float4*)s)[i];
    ushort4 o;
    o.x = f2b(v.x); o.y = f2b(v.y); o.z = f2b(v.z); o.w = f2b(v.w);
    ((ushort4*)d)[i] = o;
}

struct WPack { const float* s[6]; unsigned short* d[6]; };
__global__ __launch_bounds__(256) void convert_w(WPack p)
{
    const int mat = blockIdx.x >> 8;
    const int k = blockIdx.x & 255;
    const int c = threadIdx.x;
    p.d[mat][(size_t)c * DD + k] = f2b(p.s[mat][(size_t)k * DD + c]);
}

// ---------------------------------------------------------------------------
// V transposes with the PV-fragment permutation baked in.
// Within each 32-m block, position p = g*8+j holds actual
// m-offset r = (j>>2)*16 + g*4 + (j&3); PV B-frag = one contiguous 16B load.
// ---------------------------------------------------------------------------
__global__ __launch_bounds__(256) void transpose_all(
    const unsigned short* __restrict__ visV,
    const unsigned short* __restrict__ amrV,
    unsigned short* __restrict__ VTv, unsigned short* __restrict__ VTa)
{
    const int bx = blockIdx.x;
    const unsigned short* X; unsigned short* VT; int SEQ, mb;
    if (bx < 16) { X = visV; VT = VTv; SEQ = MM; mb = bx; }
    else         { X = amrV; VT = VTa; SEQ = NN; mb = bx - 16; }
    const int m = mb * 256 + threadIdx.x;
    const int r = m & 31;
    const int p = ((r & 15) >> 2) * 8 + (r >> 4) * 4 + (r & 3);
    const int mstore = (m & ~31) | p;
    const int c0 = blockIdx.y * 8;
    const int b = blockIdx.z;
    const bf16x8 v = *(const bf16x8*)&X[((size_t)b * SEQ + m) * DD + c0];
    #pragma unroll
    for (int j = 0; j < 8; ++j)
        VT[((size_t)b * DD + c0 + j) * SEQ + mstore] = (unsigned short)v[j];
}

// ---------------------------------------------------------------------------
// Shared 64x64 MFMA GEMM tile body (K=256)
// ---------------------------------------------------------------------------
template<bool OUTPROJ>
__device__ __forceinline__ void gemm_tile(
    const unsigned short* __restrict__ A,
    const unsigned short* __restrict__ Wt,
    float outscale,
    const float* __restrict__ bias,
    const float* __restrict__ feats,
    unsigned short* __restrict__ Cb,
    float* __restrict__ Cf,
    int r0, int c0,
    unsigned short (*As)[72], unsigned short (*Ws)[72])
{
    const int tid = threadIdx.x;
    const int lane = tid & 63, w = tid >> 6;
    const int rq = (w >> 1) * 32, cq = (w & 1) * 32;
    const int srow = tid >> 2, skc = (tid & 3) * 16;
    const int g = lane >> 4, cl = lane & 15;

    f32x4 acc[2][2] = {};

    for (int ks = 0; ks < DD; ks += 64) {
        __syncthreads();
        {
            const unsigned short* ga = &A[(size_t)(r0 + srow) * DD + ks + skc];
            *(bf16x8*)&As[srow][skc]     = *(const bf16x8*)ga;
            *(bf16x8*)&As[srow][skc + 8] = *(const bf16x8*)(ga + 8);
            const unsigned short* gw = &Wt[(size_t)(c0 + srow) * DD + ks + skc];
            *(bf16x8*)&Ws[srow][skc]     = *(const bf16x8*)gw;
            *(bf16x8*)&Ws[srow][skc + 8] = *(const bf16x8*)(gw + 8);
        }
        __syncthreads();
        #pragma unroll
        for (int kh = 0; kh < 2; ++kh) {
            const int kk = kh * 32 + g * 8;
            const bf16x8 a0 = *(const bf16x8*)&As[rq + cl][kk];
            const bf16x8 a1 = *(const bf16x8*)&As[rq + 16 + cl][kk];
            const bf16x8 b0 = *(const bf16x8*)&Ws[cq + cl][kk];
            const bf16x8 b1 = *(const bf16x8*)&Ws[cq + 16 + cl][kk];
            acc[0][0] = __builtin_amdgcn_mfma_f32_16x16x32_bf16(a0, b0, acc[0][0], 0, 0, 0);
            acc[0][1] = __builtin_amdgcn_mfma_f32_16x16x32_bf16(a0, b1, acc[0][1], 0, 0, 0);
            acc[1][0] = __builtin_amdgcn_mfma_f32_16x16x32_bf16(a1, b0, acc[1][0], 0, 0, 0);
            acc[1][1] = __builtin_amdgcn_mfma_f32_16x16x32_bf16(a1, b1, acc[1][1], 0, 0, 0);
        }
    }

    #pragma unroll
    for (int sr = 0; sr < 2; ++sr)
    #pragma unroll
    for (int sc = 0; sc < 2; ++sc) {
        const int col = c0 + cq + sc * 16 + cl;
        #pragma unroll
        for (int reg = 0; reg < 4; ++reg) {
            const int row = r0 + rq + sr * 16 + g * 4 + reg;
            const size_t idx = (size_t)row * DD + col;
            if (OUTPROJ) {
                Cf[idx] = (acc[sr][sc][reg] + bias[col]) * feats[idx];
            } else {
                Cb[idx] = f2b(acc[sr][sc][reg] * outscale);
            }
        }
    }
}

// All 4 input projections in one launch. x: 32|32|256|256 (576), y = 4.
struct InPack {
    const unsigned short* A[4];
    const unsigned short* Wt[4];
    unsigned short* C[4];
    float scale[4];
};
__global__ __launch_bounds__(256) void gemm_in(InPack p)
{
    __shared__ unsigned short As[64][72];
    __shared__ unsigned short Ws[64][72];
    const int bx = blockIdx.x;
    int which, rb;
    if (bx < 32)       { which = 0; rb = bx; }
    else if (bx < 64)  { which = 1; rb = bx - 32; }
    else if (bx < 320) { which = 2; rb = bx - 64; }
    else               { which = 3; rb = bx - 320; }
    gemm_tile<false>(p.A[which], p.Wt[which], p.scale[which], nullptr, nullptr,
                     p.C[which], nullptr, rb * 64, blockIdx.y * 64, As, Ws);
}

// Both output projections in one launch. x: 32 amr | 256 vis (288), y = 4.
struct OutPack {
    const unsigned short* A[2];
    const unsigned short* Wt[2];
    const float* bias[2];
    const float* feats[2];
    float* O[2];
};
__global__ __launch_bounds__(256) void gemm_out(OutPack p)
{
    __shared__ unsigned short As[64][72];
    __shared__ unsigned short Ws[64][72];
    const int bx = blockIdx.x;
    const int which = (bx < 32) ? 0 : 1;
    const int rb = (bx < 32) ? bx : bx - 32;
    gemm_tile<true>(p.A[which], p.Wt[which], 1.f, p.bias[which], p.feats[which],
                    nullptr, p.O[which], rb * 64, blockIdx.y * 64, As, Ws);
}

// ---------------------------------------------------------------------------
// Attention body v7: 64 queries per wave (4 q-groups share every K/V frag).
// Zero-LDS P via swapped QK^T + cvt_pk + permuted VT (single 16B V loads).
// Per 64-key tile: 8x16B VMEM, 16 QK MFMA + 16 PV MFMA, no DS ops.
// Hoisted base pointers, K prefetched one tile ahead.
// ---------------------------------------------------------------------------
template<int SEQK, int SPLIT, bool HAS_MASK>
__device__ __forceinline__ void attn_body(
    int bid,
    const unsigned short* __restrict__ Qb,
    const unsigned short* __restrict__ Kb,
    const unsigned short* __restrict__ VTb,
    const int* __restrict__ mask,
    unsigned short* __restrict__ ctx,
    float* __restrict__ Pl, unsigned short* __restrict__ PaccB,
    int NQ, float* maskadd)
{
    constexpr int KCHUNK = SEQK / SPLIT;   // 512
    constexpr int NT = KCHUNK / 64;        // 8

    const int tid = threadIdx.x;
    const int lane = tid & 63, w = tid >> 6;
    const int g = lane >> 4, cl = lane & 15;

    const int nqt = NQ / 256;
    int bi = bid;
    const int sp = bi % SPLIT; bi /= SPLIT;
    const int qt = bi % nqt;   bi /= nqt;
    const int h  = bi % HH;
    const int b  = bi / HH;
    const int q0 = qt * 256 + w * 64;
    const int kv0 = sp * KCHUNK;

    if (HAS_MASK) {
        for (int i = tid; i < SEQK; i += 256)
            maskadd[i] = mask[b * SEQK + i] ? -1e30f : 0.f;
        __syncthreads();
    }

    // Q A-frags: 4 q-groups of 16 rows each
    bf16x8 aq[4];
    #pragma unroll
    for (int qg = 0; qg < 4; ++qg)
        aq[qg] = *(const bf16x8*)
            &Qb[((size_t)b * NQ + q0 + qg * 16 + cl) * DD + h * HDD + g * 8];

    // hoisted bases (per-tile advance is a constant stride)
    const unsigned short* Kp0 = Kb + (size_t)b * SEQK * DD + h * HDD + g * 8
                                   + (size_t)(kv0 + cl) * DD;
    const unsigned short* Vp0 = VTb + ((size_t)b * DD + h * HDD + cl) * SEQK
                                    + kv0 + g * 8;

    float lsum[4] = {0.f, 0.f, 0.f, 0.f};
    f32x4 acc[4][2] = {};   // [qg][sub]

    bf16x8 Kc[4], Kn[4];
    #pragma unroll
    for (int kf = 0; kf < 4; ++kf)
        Kc[kf] = *(const bf16x8*)(Kp0 + (size_t)(kf * 16) * DD);

    for (int t = 0; t < NT; ++t) {
        const int m0 = kv0 + t * 64;

        // prefetch next K tile's frags
        if (t + 1 < NT) {
            const unsigned short* kp = Kp0 + (size_t)((t + 1) * 64) * DD;
            #pragma unroll
            for (int kf = 0; kf < 4; ++kf)
                Kn[kf] = *(const bf16x8*)(kp + (size_t)(kf * 16) * DD);
        }

        // V B-frags: single 16B loads from permuted VT (issued early)
        bf16x8 vv[2][2];
        #pragma unroll
        for (int mh = 0; mh < 2; ++mh)
            #pragma unroll
            for (int sub = 0; sub < 2; ++sub)
                vv[mh][sub] = *(const bf16x8*)
                    (Vp0 + (size_t)(sub * 16) * SEQK + t * 64 + mh * 32);

        // QK^T + softmax, processed in kf-pairs to cap register liveness
        uint2 X[4][4];
        #pragma unroll
        for (int kh = 0; kh < 2; ++kh) {
            f32x4 s[4][2];
            #pragma unroll
            for (int k2 = 0; k2 < 2; ++k2) {
                const f32x4 z = {0.f, 0.f, 0.f, 0.f};
                const bf16x8 kfrag = Kc[kh * 2 + k2];
                #pragma unroll
                for (int qg = 0; qg < 4; ++qg)
                    s[qg][k2] = __builtin_amdgcn_mfma_f32_16x16x32_bf16(
                        kfrag, aq[qg], z, 0, 0, 0);
            }
            #pragma unroll
            for (int k2 = 0; k2 < 2; ++k2) {
                const int kf = kh * 2 + k2;
                f32x4 madd;
                if (HAS_MASK)
                    madd = *(const f32x4*)&maskadd[m0 + kf * 16 + g * 4];
                #pragma unroll
                for (int qg = 0; qg < 4; ++qg) {
                    const float p0 = exp2f(s[qg][k2][0] + (HAS_MASK ? madd[0] : 0.f));
                    const float p1 = exp2f(s[qg][k2][1] + (HAS_MASK ? madd[1] : 0.f));
                    const float p2 = exp2f(s[qg][k2][2] + (HAS_MASK ? madd[2] : 0.f));
                    const float p3 = exp2f(s[qg][k2][3] + (HAS_MASK ? madd[3] : 0.f));
                    lsum[qg] += (p0 + p1) + (p2 + p3);
                    X[qg][kf].x = cvt_pk_bf16(p0, p1);
                    X[qg][kf].y = cvt_pk_bf16(p2, p3);
                }
            }
        }

        // PV: pa[qg] = [X[2mh].x, X[2mh].y, X[2mh+1].x, X[2mh+1].y]
        #pragma unroll
        for (int mh = 0; mh < 2; ++mh) {
            union { u32x4 u; bf16x8 b; } pa[4];
            #pragma unroll
            for (int qg = 0; qg < 4; ++qg) {
                pa[qg].u[0] = X[qg][mh * 2].x;
                pa[qg].u[1] = X[qg][mh * 2].y;
                pa[qg].u[2] = X[qg][mh * 2 + 1].x;
                pa[qg].u[3] = X[qg][mh * 2 + 1].y;
            }
            #pragma unroll
            for (int sub = 0; sub < 2; ++sub)
                #pragma unroll
                for (int qg = 0; qg < 4; ++qg)
                    acc[qg][sub] = __builtin_amdgcn_mfma_f32_16x16x32_bf16(
                        pa[qg].b, vv[mh][sub], acc[qg][sub], 0, 0, 0);
        }

        #pragma unroll
        for (int kf = 0; kf < 4; ++kf) Kc[kf] = Kn[kf];
    }

    // total l per q=cl: reduce across the 4 g-groups
    #pragma unroll
    for (int qg = 0; qg < 4; ++qg) {
        lsum[qg] += __shfl_xor(lsum[qg], 16);
        lsum[qg] += __shfl_xor(lsum[qg], 32);
    }

    if (SPLIT > 1) {
        const int pb = bid;
        #pragma unroll
        for (int qg = 0; qg < 4; ++qg) {
            #pragma unroll
            for (int sub = 0; sub < 2; ++sub)
                #pragma unroll
                for (int reg = 0; reg < 4; ++reg) {
                    const int wq = w * 64 + qg * 16 + g * 4 + reg;
                    PaccB[((size_t)pb * 256 + wq) * 32 + sub * 16 + cl]
                        = f2b(acc[qg][sub][reg]);
                }
            if (g == 0)
                Pl[(size_t)pb * 256 + w * 64 + qg * 16 + cl] = lsum[qg];
        }
    } else {
        // redistribute l: acc rows are q = g*4+reg; lsum lives at lane cl=q
        float linv[4][4];
        #pragma unroll
        for (int qg = 0; qg < 4; ++qg)
            #pragma unroll
            for (int reg = 0; reg < 4; ++reg)
                linv[qg][reg] = __shfl(lsum[qg], g * 4 + reg);
        #pragma unroll
        for (int qg = 0; qg < 4; ++qg)
            #pragma unroll
            for (int sub = 0; sub < 2; ++sub)
                #pragma unroll
                for (int reg = 0; reg < 4; ++reg) {
                    const int q = q0 + qg * 16 + g * 4 + reg;
                    ctx[((size_t)b * NQ + q) * DD + h * HDD + sub * 16 + cl]
                        = f2b(acc[qg][sub][reg] / linv[qg][reg]);
                }
    }
}

// Fused, parity-interleaved: even blocks = dir A (512, SPLIT=8),
// odd blocks = dir B (512, masked). Uniform NT=8 per block.
__global__ __launch_bounds__(256) void attn_fused(
    const unsigned short* __restrict__ amr_qk,
    const unsigned short* __restrict__ vis_qk,
    const unsigned short* __restrict__ VT_vis,
    const unsigned short* __restrict__ VT_amr,
    const int* __restrict__ mask,
    unsigned short* __restrict__ ctx1,
    float* __restrict__ Pl, unsigned short* __restrict__ PaccB)
{
    __shared__ float maskadd[NN];
    if ((blockIdx.x & 1) == 0) {
        attn_body<MM, 8, false>(blockIdx.x >> 1, amr_qk, vis_qk, VT_vis, nullptr,
                                nullptr, Pl, PaccB, NN, maskadd);
    } else {
        attn_body<NN, 1, true>(blockIdx.x >> 1, vis_qk, amr_qk, VT_amr, mask,
                               ctx1, nullptr, nullptr, MM, maskadd);
    }
}

// Combine 8 split partials (bf16 acc, f32 l): out = sum(acc)/sum(l)
// grid = 64 blocks (one per (b,h,qt)), 256 threads (thread = q).
__global__ __launch_bounds__(256) void combine_split(
    const float* __restrict__ Pl, const unsigned short* __restrict__ PaccB,
    unsigned short* __restrict__ ctx)
{
    const int q = threadIdx.x;
    const int bqt = blockIdx.x;
    const int qt = bqt & 1, h = (bqt >> 1) & 7, b = bqt >> 4;
    const int pb0 = bqt * 8;

    float denom = 0.f;
    float o[32] = {};
    #pragma unroll
    for (int sp = 0; sp < 8; ++sp) {
        const size_t base = ((size_t)(pb0 + sp) * 256 + q) * 32;
        #pragma unroll
        for (int c8 = 0; c8 < 4; ++c8) {
            const bf16x8 a = *(const bf16x8*)&PaccB[base + c8 * 8];
            #pragma unroll
            for (int j = 0; j < 8; ++j)
                o[c8 * 8 + j] += b2f((unsigned short)a[j]);
        }
        denom += Pl[(size_t)(pb0 + sp) * 256 + q];
    }
    const float inv = 1.f / denom;

    unsigned short* dst = &ctx[((size_t)b * NN + qt * 256 + q) * DD + h * HDD];
    #pragma unroll
    for (int j4 = 0; j4 < 8; ++j4) {
        ushort4 u;
        u.x = f2b(o[j4 * 4 + 0] * inv); u.y = f2b(o[j4 * 4 + 1] * inv);
        u.z = f2b(o[j4 * 4 + 2] * inv); u.w = f2b(o[j4 * 4 + 3] * inv);
        *(ushort4*)(dst + j4 * 4) = u;
    }
}

// ---------------------------------------------------------------------------
extern "C" void kernel_launch(void* const* d_in, const int* in_sizes, int n_in,
                              void* d_out, int out_size, void* d_ws, size_t ws_size,
                              hipStream_t stream)
{
    const float* amr_feats    = (const float*)d_in[0];
    const int*   amr_pad_mask = (const int*)d_in[1];
    const float* visual_feats = (const float*)d_in[2];
    const float* W_amr_qk     = (const float*)d_in[3];
    const float* W_amr_v      = (const float*)d_in[4];
    const float* W_vis_qk     = (const float*)d_in[5];
    const float* W_vis_v      = (const float*)d_in[6];
    const float* W_amr_out    = (const float*)d_in[7];
    const float* b_amr_out    = (const float*)d_in[8];
    const float* W_vis_out    = (const float*)d_in[9];
    const float* b_vis_out    = (const float*)d_in[10];

    // bf16 workspace (u16 offsets), total 48.0 MB
    unsigned short* ws = (unsigned short*)d_ws;
    unsigned short* amr_fb     = ws;                    // dead after gemm_in
    unsigned short* vis_fb     = ws + 524288;           // dead after gemm_in
    unsigned short* Wt_amr_qk  = ws + 4718592;
    unsigned short* Wt_amr_v   = ws + 4784128;
    unsigned short* Wt_vis_qk  = ws + 4849664;
    unsigned short* Wt_vis_v   = ws + 4915200;
    unsigned short* Wt_amr_out = ws + 4980736;
    unsigned short* Wt_vis_out = ws + 5046272;
    unsigned short* amr_qk_b   = ws + 5111808;
    unsigned short* amr_v_b    = ws + 5636096;
    unsigned short* vis_qk_b   = ws + 6160384;
    unsigned short* vis_v_b    = ws + 10354688;
    unsigned short* ctx0_b     = ws + 14548992;
    unsigned short* ctx1_b     = ws + 15073280;
    unsigned short* VT_vis     = ws + 19267584;
    unsigned short* VT_amr     = ws + 23461888;
    // split partials alias the dead amr_fb/vis_fb staging region
    // Pl f32 [512*256] = 0..262144 u16; PaccB bf16 [512*256*32] = 262144..4456448
    float* Pl             = (float*)ws;
    unsigned short* PaccB = ws + 262144;

    float* out0 = (float*)d_out;
    float* out1 = out0 + (size_t)BB * NN * DD;

    // sqrt( HD^-0.5 * log2(e) ) folded into BOTH qk projections -> exp2 domain
    const float SQS = 0.50500976f;

    // 0) conversions (2 launches)
    convert_feats<<<4608, 256, 0, stream>>>(amr_feats, visual_feats, amr_fb, vis_fb);
    WPack wp;
    wp.s[0] = W_amr_qk;  wp.d[0] = Wt_amr_qk;
    wp.s[1] = W_amr_v;   wp.d[1] = Wt_amr_v;
    wp.s[2] = W_vis_qk;  wp.d[2] = Wt_vis_qk;
    wp.s[3] = W_vis_v;   wp.d[3] = Wt_vis_v;
    wp.s[4] = W_amr_out; wp.d[4] = Wt_amr_out;
    wp.s[5] = W_vis_out; wp.d[5] = Wt_vis_out;
    convert_w<<<1536, 256, 0, stream>>>(wp);

    // 1) all 4 input projections, one launch
    InPack ip;
    ip.A[0] = amr_fb; ip.Wt[0] = Wt_amr_qk; ip.C[0] = amr_qk_b; ip.scale[0] = SQS;
    ip.A[1] = amr_fb; ip.Wt[1] = Wt_amr_v;  ip.C[1] = amr_v_b;  ip.scale[1] = 1.f;
    ip.A[2] = vis_fb; ip.Wt[2] = Wt_vis_qk; ip.C[2] = vis_qk_b; ip.scale[2] = SQS;
    ip.A[3] = vis_fb; ip.Wt[3] = Wt_vis_v;  ip.C[3] = vis_v_b;  ip.scale[3] = 1.f;
    gemm_in<<<dim3(576, 4), 256, 0, stream>>>(ip);

    // 1b) V transposes (permuted layout), one launch
    transpose_all<<<dim3(18, 32, 4), 256, 0, stream>>>(vis_v_b, amr_v_b, VT_vis, VT_amr);

    // 2) both attention directions, parity-interleaved, one launch
    attn_fused<<<1024, 256, 0, stream>>>(
        amr_qk_b, vis_qk_b, VT_vis, VT_amr, amr_pad_mask, ctx1_b, Pl, PaccB);
    combine_split<<<64, 256, 0, stream>>>(Pl, PaccB, ctx0_b);

    // 3) both output projections, one launch
    OutPack op;
    op.A[0] = ctx0_b; op.Wt[0] = Wt_amr_out; op.bias[0] = b_amr_out;
    op.feats[0] = amr_feats;    op.O[0] = out0;
    op.A[1] = ctx1_b; op.Wt[1] = Wt_vis_out; op.bias[1] = b_vis_out;
    op.feats[1] = visual_feats; op.O[1] = out1;
    gemm_out<<<dim3(288, 4), 256, 0, stream>>>(op);
}